// Round 1
// baseline (277.688 us; speedup 1.0000x reference)
//
#include <hip/hip_runtime.h>

#define NNODES 100000
#define NEDGES 300000
#define KF     1433
#define KP     1536   // padded K so k = lane + 64*it (it<23) stays in-bounds; zero-filled tail
#define HID    16
#define NC     7

// ---------------------------------------------------------------------------
// Kernel A: y = x @ w1   ([NNODES,KF] fp32 x [KF,HID] fp32 -> [NNODES,HID])
// W1 staged transposed in LDS (98 KB). Each wave owns 8 rows; lanes split K
// with stride 64 (coalesced b32 global loads, stride-1 LDS reads). Butterfly
// shuffle reduction at the end.
// ---------------------------------------------------------------------------
__global__ __launch_bounds__(512) void gemm_xw1(const float* __restrict__ x,
                                                const float* __restrict__ w1,
                                                float* __restrict__ y) {
    __shared__ float w1t[HID * KP];  // [j][k], 98304 bytes

    const int tid = threadIdx.x;

    // Stage w1 transposed + zero-pad k in [KF, KP)
    for (int k = tid; k < KP; k += 512) {
        if (k < KF) {
            const float* r = w1 + k * HID;
            #pragma unroll
            for (int j = 0; j < HID; ++j) w1t[j * KP + k] = r[j];
        } else {
            #pragma unroll
            for (int j = 0; j < HID; ++j) w1t[j * KP + k] = 0.f;
        }
    }
    __syncthreads();

    const int wave = tid >> 6;
    const int lane = tid & 63;

    // block covers 64 rows per pass (8 waves x 8 rows); grid-stride over passes
    for (int base = blockIdx.x * 64 + wave * 8; base < NNODES; base += 256 * 64) {
        float acc[8][HID];
        #pragma unroll
        for (int r = 0; r < 8; ++r)
            #pragma unroll
            for (int j = 0; j < HID; ++j) acc[r][j] = 0.f;

        for (int it = 0; it < 23; ++it) {
            const int k = lane + it * 64;   // k <= 1471 < KP
            float xv[8];
            #pragma unroll
            for (int r = 0; r < 8; ++r) {
                const int row = base + r;
                xv[r] = (row < NNODES && k < KF) ? x[row * KF + k] : 0.f;
            }
            #pragma unroll
            for (int j = 0; j < HID; ++j) {
                const float wv = w1t[j * KP + k];   // zero-filled beyond KF
                #pragma unroll
                for (int r = 0; r < 8; ++r) acc[r][j] += xv[r] * wv;
            }
        }

        // reduce across 64 lanes; lane j (0..15) keeps column j of each row
        #pragma unroll
        for (int r = 0; r < 8; ++r) {
            const int row = base + r;
            float keep = 0.f;
            #pragma unroll
            for (int j = 0; j < HID; ++j) {
                float v = acc[r][j];
                v += __shfl_xor(v, 1);
                v += __shfl_xor(v, 2);
                v += __shfl_xor(v, 4);
                v += __shfl_xor(v, 8);
                v += __shfl_xor(v, 16);
                v += __shfl_xor(v, 32);
                if ((lane & 15) == j) keep = v;
            }
            if (row < NNODES && lane < HID) y[row * HID + lane] = keep;
        }
    }
}

// ---------------------------------------------------------------------------
// Kernel B: zero the aggregation buffer
// ---------------------------------------------------------------------------
__global__ __launch_bounds__(256) void zero_agg(float4* __restrict__ agg4) {
    const int i = blockIdx.x * 256 + threadIdx.x;
    if (i < NNODES * HID / 4) agg4[i] = make_float4(0.f, 0.f, 0.f, 0.f);
}

// ---------------------------------------------------------------------------
// Kernel C: agg[dst] += y[src]  (thread per (edge, j))
// ---------------------------------------------------------------------------
__global__ __launch_bounds__(256) void scatter_add(const int* __restrict__ ei,
                                                   const float* __restrict__ y,
                                                   float* __restrict__ agg) {
    const int t = blockIdx.x * 256 + threadIdx.x;
    const int e = t >> 4;
    const int j = t & 15;
    if (e < NEDGES) {
        const int s = ei[e];           // src
        const int d = ei[NEDGES + e];  // dst
        atomicAdd(agg + d * HID + j, y[s * HID + j]);
    }
}

// ---------------------------------------------------------------------------
// Kernel D: out = sigmoid(relu((1+eps)*y + agg + b1) @ w2 + b2)
// ---------------------------------------------------------------------------
__global__ __launch_bounds__(256) void mlp_tail(const float* __restrict__ y,
                                                const float* __restrict__ agg,
                                                const float* __restrict__ b1,
                                                const float* __restrict__ w2,
                                                const float* __restrict__ b2,
                                                const float* __restrict__ epsp,
                                                float* __restrict__ out) {
    __shared__ float sw2[HID * NC];
    __shared__ float sb1[HID];
    __shared__ float sb2[NC];
    __shared__ float seps;

    const int t = threadIdx.x;
    if (t < HID * NC) sw2[t] = w2[t];
    if (t < HID)      sb1[t] = b1[t];
    if (t < NC)       sb2[t] = b2[t];
    if (t == 0)       seps = epsp[0];
    __syncthreads();

    const int i = blockIdx.x * 256 + t;
    if (i >= NNODES) return;

    const float co = 1.f + seps;
    const float4* y4 = (const float4*)(y + i * HID);
    const float4* a4 = (const float4*)(agg + i * HID);

    float h[HID];
    #pragma unroll
    for (int q = 0; q < 4; ++q) {
        const float4 yv = y4[q];
        const float4 av = a4[q];
        h[q * 4 + 0] = fmaxf(co * yv.x + av.x + sb1[q * 4 + 0], 0.f);
        h[q * 4 + 1] = fmaxf(co * yv.y + av.y + sb1[q * 4 + 1], 0.f);
        h[q * 4 + 2] = fmaxf(co * yv.z + av.z + sb1[q * 4 + 2], 0.f);
        h[q * 4 + 3] = fmaxf(co * yv.w + av.w + sb1[q * 4 + 3], 0.f);
    }

    #pragma unroll
    for (int c = 0; c < NC; ++c) {
        float s = sb2[c];
        #pragma unroll
        for (int j = 0; j < HID; ++j) s += h[j] * sw2[j * NC + c];
        out[i * NC + c] = 1.f / (1.f + __expf(-s));
    }
}

// ---------------------------------------------------------------------------
extern "C" void kernel_launch(void* const* d_in, const int* in_sizes, int n_in,
                              void* d_out, int out_size, void* d_ws, size_t ws_size,
                              hipStream_t stream) {
    const float* x   = (const float*)d_in[0];
    const int*   ei  = (const int*)d_in[1];
    const float* w1  = (const float*)d_in[2];
    const float* b1  = (const float*)d_in[3];
    const float* w2  = (const float*)d_in[4];
    const float* b2  = (const float*)d_in[5];
    const float* eps = (const float*)d_in[6];
    float* out = (float*)d_out;

    float* y   = (float*)d_ws;                  // NNODES*HID floats (6.4 MB)
    float* agg = y + (size_t)NNODES * HID;      // NNODES*HID floats (6.4 MB)

    gemm_xw1<<<256, 512, 0, stream>>>(x, w1, y);
    zero_agg<<<(NNODES * HID / 4 + 255) / 256, 256, 0, stream>>>((float4*)agg);
    scatter_add<<<(NEDGES * 16 + 255) / 256, 256, 0, stream>>>(ei, y, agg);
    mlp_tail<<<(NNODES + 255) / 256, 256, 0, stream>>>(y, agg, b1, w2, b2, eps, out);
}